// Round 1
// baseline (5362.746 us; speedup 1.0000x reference)
//
#include <hip/hip_runtime.h>

#define CV 768
#define VOCAB 50000
#define DNB 300
#define HDIM 768
#define TOTAL_IN 1671   // CV + 3*DNB + 3
#define CSTRIDE 1672    // padded row stride (16B-aligned rows)
#define ROWS 2048       // B*P
#define RTILE 32
#define NCHUNK 8
#define VCHUNK 6250     // 8*6250 = 50000 exactly
#define VBATCH 512

__device__ __forceinline__ float block_sum256(float v, float* ws) {
#pragma unroll
  for (int off = 32; off > 0; off >>= 1) v += __shfl_xor(v, off, 64);
  int tid = threadIdx.x;
  if ((tid & 63) == 0) ws[tid >> 6] = v;
  __syncthreads();
  float s = ws[0] + ws[1] + ws[2] + ws[3];
  __syncthreads();
  return s;
}

// ---------------- Kernel 1: q = v_seq / max(||v_seq||, 1e-12) ----------------
__global__ __launch_bounds__(256) void normalize_kernel(
    const float* __restrict__ v_seq, float* __restrict__ q) {
  __shared__ float ws[4];
  int row = blockIdx.x, tid = threadIdx.x;
  const float* x = v_seq + (size_t)row * CV;
  float* qr = q + (size_t)row * CV;
  float x0 = x[tid], x1 = x[tid + 256], x2 = x[tid + 512];
  float s = block_sum256(x0 * x0 + x1 * x1 + x2 * x2, ws);
  float denom = fmaxf(sqrtf(s), 1e-12f);
  qr[tid] = x0 / denom;
  qr[tid + 256] = x1 / denom;
  qr[tid + 512] = x2 / denom;
}

// ---------------- Kernel 2: fused scores + per-chunk top-3 ----------------
// grid = (ROWS/RTILE, NCHUNK); block = 256.
// Each block: 32 q-rows x 6250 vocab entries. Per batch of 512 v (2 per thread),
// register-block 32 rows x 2 v; dots staged in LDS; 8 threads/row maintain top-3.
__global__ __launch_bounds__(256) void score_topk_kernel(
    const float* __restrict__ q, const float* __restrict__ T,
    float* __restrict__ pval, int* __restrict__ pidx) {
  __shared__ float dot_lds[RTILE][VBATCH];  // 64 KB
  __shared__ float mval[RTILE][8][3];
  __shared__ int midx[RTILE][8][3];

  int tid = threadIdx.x;
  int row0 = blockIdx.x * RTILE;
  int v0 = blockIdx.y * VCHUNK;
  const float* __restrict__ qt = q + (size_t)row0 * CV;  // block-uniform

  int g = tid >> 3;  // row within tile (0..31)
  int j = tid & 7;   // scanner lane within row
  float t0v = -__builtin_inff(), t1v = t0v, t2v = t0v;
  int t0i = -1, t1i = -1, t2i = -1;

  const int nbatch = (VCHUNK + VBATCH - 1) / VBATCH;  // 13
  for (int b = 0; b < nbatch; ++b) {
    int la = b * VBATCH + tid;
    int lb = la + 256;
    bool okA = la < VCHUNK, okB = lb < VCHUNK;
    const float* tA = T + (size_t)(okA ? (v0 + la) : 0) * CV;
    const float* tB = T + (size_t)(okB ? (v0 + lb) : 0) * CV;
    float accA[RTILE], accB[RTILE];
#pragma unroll
    for (int r = 0; r < RTILE; ++r) { accA[r] = 0.f; accB[r] = 0.f; }
#pragma unroll 2
    for (int c = 0; c < CV; c += 4) {
      float4 a4 = *reinterpret_cast<const float4*>(tA + c);
      float4 b4 = *reinterpret_cast<const float4*>(tB + c);
#pragma unroll
      for (int r = 0; r < RTILE; ++r) {
        float4 q4 = *reinterpret_cast<const float4*>(qt + r * CV + c);  // uniform -> s_load
        accA[r] += a4.x * q4.x + a4.y * q4.y + a4.z * q4.z + a4.w * q4.w;
        accB[r] += b4.x * q4.x + b4.y * q4.y + b4.z * q4.z + b4.w * q4.w;
      }
    }
#pragma unroll
    for (int r = 0; r < RTILE; ++r) {
      dot_lds[r][tid] = okA ? accA[r] : -__builtin_inff();
      dot_lds[r][tid + 256] = okB ? accB[r] : -__builtin_inff();
    }
    __syncthreads();
    int vbase = v0 + b * VBATCH;
#pragma unroll
    for (int i = 0; i < VBATCH / 8; ++i) {
      int sl = j + 8 * i;  // ascending index order -> strict > keeps lower idx on ties
      float d = dot_lds[g][sl];
      int di = vbase + sl;
      if (d > t0v)      { t2v = t1v; t2i = t1i; t1v = t0v; t1i = t0i; t0v = d; t0i = di; }
      else if (d > t1v) { t2v = t1v; t2i = t1i; t1v = d; t1i = di; }
      else if (d > t2v) { t2v = d; t2i = di; }
    }
    __syncthreads();
  }
  mval[g][j][0] = t0v; mval[g][j][1] = t1v; mval[g][j][2] = t2v;
  midx[g][j][0] = t0i; midx[g][j][1] = t1i; midx[g][j][2] = t2i;
  __syncthreads();
  if (tid < RTILE) {
    float b0v = -__builtin_inff(), b1v = b0v, b2v = b0v;
    int b0i = -1, b1i = -1, b2i = -1;
    for (int jj = 0; jj < 8; ++jj) {
#pragma unroll
      for (int e = 0; e < 3; ++e) {
        float d = mval[tid][jj][e];
        int di = midx[tid][jj][e];
        if (d > b0v || (d == b0v && (unsigned)di < (unsigned)b0i)) {
          b2v = b1v; b2i = b1i; b1v = b0v; b1i = b0i; b0v = d; b0i = di;
        } else if (d > b1v || (d == b1v && (unsigned)di < (unsigned)b1i)) {
          b2v = b1v; b2i = b1i; b1v = d; b1i = di;
        } else if (d > b2v || (d == b2v && (unsigned)di < (unsigned)b2i)) {
          b2v = d; b2i = di;
        }
      }
    }
    int base = (row0 + tid) * (NCHUNK * 3) + blockIdx.y * 3;
    pval[base + 0] = b0v; pval[base + 1] = b1v; pval[base + 2] = b2v;
    pidx[base + 0] = b0i; pidx[base + 1] = b1i; pidx[base + 2] = b2i;
  }
}

// ---------------- Kernel 3: merge per-chunk top-3 -> global top-3 ----------------
__global__ __launch_bounds__(256) void merge_topk_kernel(
    const float* __restrict__ pval, const int* __restrict__ pidx,
    float* __restrict__ val, int* __restrict__ idx) {
  int row = blockIdx.x * 256 + threadIdx.x;
  if (row >= ROWS) return;
  float b0v = -__builtin_inff(), b1v = b0v, b2v = b0v;
  int b0i = -1, b1i = -1, b2i = -1;
#pragma unroll
  for (int c = 0; c < NCHUNK * 3; ++c) {
    float d = pval[row * (NCHUNK * 3) + c];
    int di = pidx[row * (NCHUNK * 3) + c];
    if (d > b0v || (d == b0v && (unsigned)di < (unsigned)b0i)) {
      b2v = b1v; b2i = b1i; b1v = b0v; b1i = b0i; b0v = d; b0i = di;
    } else if (d > b1v || (d == b1v && (unsigned)di < (unsigned)b1i)) {
      b2v = b1v; b2i = b1i; b1v = d; b1i = di;
    } else if (d > b2v || (d == b2v && (unsigned)di < (unsigned)b2i)) {
      b2v = d; b2i = di;
    }
  }
  val[row * 3 + 0] = b0v; val[row * 3 + 1] = b1v; val[row * 3 + 2] = b2v;
  idx[row * 3 + 0] = b0i; idx[row * 3 + 1] = b1i; idx[row * 3 + 2] = b2i;
}

// ---------------- Kernel 4: combined = [v_seq | nb_vecs[idx] | val] ----------------
__global__ __launch_bounds__(256) void gather_concat_kernel(
    const float* __restrict__ v_seq, const float* __restrict__ nb,
    const float* __restrict__ val, const int* __restrict__ idx,
    float* __restrict__ combined) {
  int row = blockIdx.x, tid = threadIdx.x;
  float* c = combined + (size_t)row * CSTRIDE;
  const float* vs = v_seq + (size_t)row * CV;
  if (tid < 192)
    *reinterpret_cast<float4*>(c + tid * 4) =
        *reinterpret_cast<const float4*>(vs + tid * 4);
  int i0 = idx[row * 3 + 0], i1 = idx[row * 3 + 1], i2 = idx[row * 3 + 2];
  if (tid < 75) {
    *reinterpret_cast<float4*>(c + CV + tid * 4) =
        *reinterpret_cast<const float4*>(nb + (size_t)i0 * DNB + tid * 4);
    *reinterpret_cast<float4*>(c + CV + DNB + tid * 4) =
        *reinterpret_cast<const float4*>(nb + (size_t)i1 * DNB + tid * 4);
    *reinterpret_cast<float4*>(c + CV + 2 * DNB + tid * 4) =
        *reinterpret_cast<const float4*>(nb + (size_t)i2 * DNB + tid * 4);
  }
  if (tid < 3) c[CV + 3 * DNB + tid] = val[row * 3 + tid];
  if (tid == 3) c[TOTAL_IN] = 0.f;  // padding slot
}

// ---------------- Kernel 5/6: tiled fp32 GEMM + bias (+ optional erf-GELU) ----------------
// C[M][N] = act(A[M][Kdim] @ Bm[Kdim][N] + bias). Tiles 64x64x32, 4x4 micro.
__global__ __launch_bounds__(256) void gemm_bias_act(
    const float* __restrict__ A, int lda, int Kdim,
    const float* __restrict__ Bm, const float* __restrict__ bias,
    float* __restrict__ C, int N, int act) {
  __shared__ float As[32][80];  // transposed [k][m], stride 80 -> 16B-aligned rows
  __shared__ float Bs[32][80];  // [k][n]
  int tid = threadIdx.x;
  int m0 = blockIdx.x * 64, n0 = blockIdx.y * 64;
  int tm = tid >> 4, tn = tid & 15;
  float acc[4][4] = {{0.f, 0.f, 0.f, 0.f}};
  int mr = tid & 63;
  int kq0 = (tid >> 6) * 4;
  for (int k0 = 0; k0 < Kdim; k0 += 32) {
#pragma unroll
    for (int pass = 0; pass < 2; ++pass) {
      int kq = kq0 + pass * 16;
      int kg = k0 + kq;
      const float* ap = A + (size_t)(m0 + mr) * lda;
      float4 av;
      if (kg + 3 < Kdim) {
        av = *reinterpret_cast<const float4*>(ap + kg);
      } else {
        float t[4] = {0.f, 0.f, 0.f, 0.f};
#pragma unroll
        for (int u = 0; u < 4; ++u)
          if (kg + u < Kdim) t[u] = ap[kg + u];
        av = make_float4(t[0], t[1], t[2], t[3]);
      }
      As[kq + 0][mr] = av.x; As[kq + 1][mr] = av.y;
      As[kq + 2][mr] = av.z; As[kq + 3][mr] = av.w;
    }
#pragma unroll
    for (int pass = 0; pass < 2; ++pass) {
      int kr = pass * 16 + (tid >> 4);
      int nq = (tid & 15) * 4;
      float4 bv = make_float4(0.f, 0.f, 0.f, 0.f);
      if (k0 + kr < Kdim)
        bv = *reinterpret_cast<const float4*>(Bm + (size_t)(k0 + kr) * N + n0 + nq);
      *reinterpret_cast<float4*>(&Bs[kr][nq]) = bv;
    }
    __syncthreads();
#pragma unroll
    for (int kk = 0; kk < 32; ++kk) {
      float4 a4 = *reinterpret_cast<const float4*>(&As[kk][tm * 4]);
      float4 b4 = *reinterpret_cast<const float4*>(&Bs[kk][tn * 4]);
      float a[4] = {a4.x, a4.y, a4.z, a4.w};
      float bb[4] = {b4.x, b4.y, b4.z, b4.w};
#pragma unroll
      for (int i2 = 0; i2 < 4; ++i2)
#pragma unroll
        for (int j2 = 0; j2 < 4; ++j2) acc[i2][j2] += a[i2] * bb[j2];
    }
    __syncthreads();
  }
#pragma unroll
  for (int i2 = 0; i2 < 4; ++i2) {
    float4 o;
    float* orow = C + (size_t)(m0 + tm * 4 + i2) * N + n0 + tn * 4;
#pragma unroll
    for (int j2 = 0; j2 < 4; ++j2) {
      float x = acc[i2][j2] + bias[n0 + tn * 4 + j2];
      if (act) x = 0.5f * x * (1.0f + erff(x * 0.70710678118654752f));
      reinterpret_cast<float*>(&o)[j2] = x;
    }
    *reinterpret_cast<float4*>(orow) = o;
  }
}

// ---------------- Kernel 7: in-place LayerNorm (no affine, eps=1e-5) ----------------
__global__ __launch_bounds__(256) void layernorm_kernel(float* __restrict__ C) {
  __shared__ float ws[4];
  int row = blockIdx.x, tid = threadIdx.x;
  float* x = C + (size_t)row * CV;
  float x0 = x[tid], x1 = x[tid + 256], x2 = x[tid + 512];
  float mu = block_sum256(x0 + x1 + x2, ws) * (1.0f / 768.0f);
  float d0 = x0 - mu, d1 = x1 - mu, d2 = x2 - mu;
  float var = block_sum256(d0 * d0 + d1 * d1 + d2 * d2, ws) * (1.0f / 768.0f);
  float inv = 1.0f / sqrtf(var + 1e-5f);
  x[tid] = d0 * inv; x[tid + 256] = d1 * inv; x[tid + 512] = d2 * inv;
}

extern "C" void kernel_launch(void* const* d_in, const int* in_sizes, int n_in,
                              void* d_out, int out_size, void* d_ws, size_t ws_size,
                              hipStream_t stream) {
  const float* v_seq = (const float*)d_in[0];
  const float* T = (const float*)d_in[1];
  const float* nb = (const float*)d_in[2];
  const float* W1 = (const float*)d_in[3];
  const float* b1 = (const float*)d_in[4];
  const float* W2 = (const float*)d_in[5];
  const float* b2 = (const float*)d_in[6];
  float* out = (float*)d_out;

  float* ws = (float*)d_ws;
  float* q = ws;                                   // 2048*768
  float* combined = q + (size_t)ROWS * CV;         // 2048*1672
  float* h = combined + (size_t)ROWS * CSTRIDE;    // 2048*768
  float* pval = h + (size_t)ROWS * HDIM;           // 2048*24
  int* pidx = (int*)(pval + (size_t)ROWS * NCHUNK * 3);
  float* val = (float*)(pidx + (size_t)ROWS * NCHUNK * 3);  // 2048*3
  int* idx = (int*)(val + (size_t)ROWS * 3);                // 2048*3

  normalize_kernel<<<ROWS, 256, 0, stream>>>(v_seq, q);
  score_topk_kernel<<<dim3(ROWS / RTILE, NCHUNK), 256, 0, stream>>>(q, T, pval, pidx);
  merge_topk_kernel<<<(ROWS + 255) / 256, 256, 0, stream>>>(pval, pidx, val, idx);
  gather_concat_kernel<<<ROWS, 256, 0, stream>>>(v_seq, nb, val, idx, combined);
  gemm_bias_act<<<dim3(ROWS / 64, HDIM / 64), 256, 0, stream>>>(
      combined, CSTRIDE, TOTAL_IN, W1, b1, h, HDIM, 1);
  gemm_bias_act<<<dim3(ROWS / 64, CV / 64), 256, 0, stream>>>(
      h, HDIM, HDIM, W2, b2, out, CV, 0);
  layernorm_kernel<<<ROWS, 256, 0, stream>>>(out);
}

// Round 2
// 846.660 us; speedup vs baseline: 6.3340x; 6.3340x over previous
//
#include <hip/hip_runtime.h>
#include <hip/hip_bf16.h>

typedef unsigned short u16;
typedef __attribute__((ext_vector_type(4))) unsigned short u16x4;
typedef __attribute__((ext_vector_type(8))) short bf16x8;
typedef __attribute__((ext_vector_type(4))) float f32x4;

#define ROWS 2048
#define CV 768
#define VOCAB 50000
#define NPAD 50048
#define DNB 300
#define TOTAL_IN 1671
#define KPAD1 1696   // TOTAL_IN padded to multiple of 32
#define HD 768

__device__ __forceinline__ u16 f2bf(float f) {
  union { __hip_bfloat16 h; u16 u; } x;
  x.h = __float2bfloat16(f);
  return x.u;
}

__device__ __forceinline__ void gload16(const void* g, void* l) {
  __builtin_amdgcn_global_load_lds(
      (const __attribute__((address_space(1))) void*)g,
      (__attribute__((address_space(3))) void*)l, 16, 0, 0);
}

__device__ __forceinline__ float block_sum256(float v, float* ws) {
#pragma unroll
  for (int off = 32; off > 0; off >>= 1) v += __shfl_xor(v, off, 64);
  int tid = threadIdx.x;
  if ((tid & 63) == 0) ws[tid >> 6] = v;
  __syncthreads();
  float s = ws[0] + ws[1] + ws[2] + ws[3];
  __syncthreads();
  return s;
}

// ---------------- normalize: q (f32) and q16 (bf16) ----------------
__global__ __launch_bounds__(256) void normalize_kernel(
    const float* __restrict__ v_seq, float* __restrict__ q, u16* __restrict__ q16) {
  __shared__ float ws[4];
  int row = blockIdx.x, tid = threadIdx.x;
  const float* x = v_seq + (size_t)row * CV;
  float x0 = x[tid], x1 = x[tid + 256], x2 = x[tid + 512];
  float s = block_sum256(x0 * x0 + x1 * x1 + x2 * x2, ws);
  float denom = fmaxf(sqrtf(s), 1e-12f);
  float q0 = x0 / denom, q1 = x1 / denom, q2 = x2 / denom;
  float* qr = q + (size_t)row * CV;
  u16* qb = q16 + (size_t)row * CV;
  qr[tid] = q0; qr[tid + 256] = q1; qr[tid + 512] = q2;
  qb[tid] = f2bf(q0); qb[tid + 256] = f2bf(q1); qb[tid + 512] = f2bf(q2);
}

// ---------------- f32 -> bf16 bulk convert (float4 granularity) ----------------
__global__ __launch_bounds__(256) void cvt_bf16_kernel(
    const float* __restrict__ src, u16* __restrict__ dst, int n4) {
  int i = blockIdx.x * 256 + threadIdx.x;
  int stride = gridDim.x * 256;
  for (; i < n4; i += stride) {
    float4 v = reinterpret_cast<const float4*>(src)[i];
    u16x4 o = {f2bf(v.x), f2bf(v.y), f2bf(v.z), f2bf(v.w)};
    reinterpret_cast<u16x4*>(dst)[i] = o;
  }
}

// ---------------- transpose + convert: src[Ksrc][N] f32 -> dst[N][ldk] bf16 ----
__global__ __launch_bounds__(256) void transpose_cvt_kernel(
    const float* __restrict__ src, u16* __restrict__ dst, int Ksrc, int ldk, int N) {
  __shared__ float tile[32][33];
  int tx = threadIdx.x & 31, ty = threadIdx.x >> 5;  // 32 x 8
  int kb = blockIdx.x * 32, nb = blockIdx.y * 32;
#pragma unroll
  for (int i = 0; i < 4; ++i) {
    int k = kb + ty + i * 8, n = nb + tx;
    tile[ty + i * 8][tx] = (k < Ksrc) ? src[(size_t)k * N + n] : 0.f;
  }
  __syncthreads();
#pragma unroll
  for (int i = 0; i < 4; ++i) {
    int n = nb + ty + i * 8, k = kb + tx;
    dst[(size_t)n * ldk + k] = f2bf(tile[tx][ty + i * 8]);
  }
}

// ---------------- bf16 MFMA GEMM, B^T layout (m97 structure) ----------------
// C[m][n] = sum_k A[m][k] * B[n][k].  128x128 tile, BK=32, 4 waves (2x2 of 64x64),
// global_load_lds width-16 staging, 16x16x32 MFMA, fp32 accum.
template <int ACT, int OUTBF>
__global__ __launch_bounds__(256) void gemm_bt(
    const u16* __restrict__ A, int lda,
    const u16* __restrict__ B, int ldb, int nclamp,
    int Kdim, const float* __restrict__ bias,
    float* __restrict__ Cf, u16* __restrict__ Cb, int ldc, int n0base) {
  __shared__ __align__(16) u16 Asm[128 * 32];
  __shared__ __align__(16) u16 Bsm[128 * 32];
  int tid = threadIdx.x;
  int w = tid >> 6, lane = tid & 63;
  int wr = w >> 1, wc = w & 1;
  int m0 = blockIdx.x * 128;
  int n0 = n0base + blockIdx.y * 128;
  f32x4 acc[4][4];
#pragma unroll
  for (int i = 0; i < 4; ++i)
#pragma unroll
    for (int j = 0; j < 4; ++j) acc[i][j] = {0.f, 0.f, 0.f, 0.f};

  int r0 = tid >> 2, s0 = tid & 3;  // staging row/segment; call1 rows are +64
  int b0r = n0 + r0;       b0r = b0r > nclamp ? nclamp : b0r;
  int b1r = n0 + 64 + r0;  b1r = b1r > nclamp ? nclamp : b1r;

  for (int k0 = 0; k0 < Kdim; k0 += 32) {
    __syncthreads();
    gload16(A + (size_t)(m0 + r0) * lda + k0 + s0 * 8, Asm + w * 512);
    gload16(A + (size_t)(m0 + 64 + r0) * lda + k0 + s0 * 8, Asm + 2048 + w * 512);
    gload16(B + (size_t)b0r * ldb + k0 + s0 * 8, Bsm + w * 512);
    gload16(B + (size_t)b1r * ldb + k0 + s0 * 8, Bsm + 2048 + w * 512);
    __syncthreads();
    int l15 = lane & 15, l4 = lane >> 4;
    bf16x8 af[4], bfr[4];
#pragma unroll
    for (int mi = 0; mi < 4; ++mi)
      af[mi] = *reinterpret_cast<const bf16x8*>(Asm + (wr * 64 + mi * 16 + l15) * 32 + l4 * 8);
#pragma unroll
    for (int ni = 0; ni < 4; ++ni)
      bfr[ni] = *reinterpret_cast<const bf16x8*>(Bsm + (wc * 64 + ni * 16 + l15) * 32 + l4 * 8);
#pragma unroll
    for (int mi = 0; mi < 4; ++mi)
#pragma unroll
      for (int ni = 0; ni < 4; ++ni)
        acc[mi][ni] = __builtin_amdgcn_mfma_f32_16x16x32_bf16(af[mi], bfr[ni], acc[mi][ni], 0, 0, 0);
  }

  int l15 = lane & 15, l4 = lane >> 4;
#pragma unroll
  for (int mi = 0; mi < 4; ++mi) {
#pragma unroll
    for (int ni = 0; ni < 4; ++ni) {
      int gr = m0 + wr * 64 + mi * 16 + l4 * 4;
      int gc = n0 + wc * 64 + ni * 16 + l15;
      float bv = bias ? bias[gc] : 0.f;
#pragma unroll
      for (int r = 0; r < 4; ++r) {
        float x = acc[mi][ni][r] + bv;
        if (ACT) x = 0.5f * x * (1.0f + erff(x * 0.70710678118654752f));
        size_t co = (size_t)(gr + r) * ldc + (gc - n0base);
        if (OUTBF) Cb[co] = f2bf(x);
        else       Cf[co] = x;
      }
    }
  }
}

// ---------------- per-chunk top-8 candidates from S ----------------
__global__ __launch_bounds__(256) void topk8_chunk(
    const float* __restrict__ Sc, int ldS, int nvalid, int nbase,
    float* __restrict__ candv, int* __restrict__ candi, int cstride, int coff) {
  __shared__ float lv[256][8];
  __shared__ int li[256][8];
  int row = blockIdx.x, tid = threadIdx.x;
  const float* Sr = Sc + (size_t)row * ldS;
  float tv[8]; int ti[8];
#pragma unroll
  for (int j = 0; j < 8; ++j) { tv[j] = -__builtin_inff(); ti[j] = -1; }
  for (int n = tid; n < nvalid; n += 256) {
    float d = Sr[n];
    if (d > tv[7]) {
      tv[7] = d; ti[7] = nbase + n;
#pragma unroll
      for (int j = 7; j > 0; --j) {
        if (tv[j] > tv[j - 1]) {
          float t = tv[j]; tv[j] = tv[j - 1]; tv[j - 1] = t;
          int t2 = ti[j]; ti[j] = ti[j - 1]; ti[j - 1] = t2;
        }
      }
    }
  }
#pragma unroll
  for (int j = 0; j < 8; ++j) { lv[tid][j] = tv[j]; li[tid][j] = ti[j]; }
  __syncthreads();
  for (int s = 128; s >= 1; s >>= 1) {
    if (tid < s) {
      int pa = 0, pb = 0;
      float ov[8]; int oi[8];
#pragma unroll
      for (int k2 = 0; k2 < 8; ++k2) {
        float va = lv[tid][pa], vb = lv[tid + s][pb];
        int ja = li[tid][pa], jb = li[tid + s][pb];
        bool ta = (va >= vb);
        ov[k2] = ta ? va : vb;
        oi[k2] = ta ? ja : jb;
        pa += ta ? 1 : 0;
        pb += ta ? 0 : 1;
      }
#pragma unroll
      for (int k2 = 0; k2 < 8; ++k2) { lv[tid][k2] = ov[k2]; li[tid][k2] = oi[k2]; }
    }
    __syncthreads();
  }
  if (tid == 0) {
#pragma unroll
    for (int j = 0; j < 8; ++j) {
      candv[(size_t)row * cstride + coff + j] = lv[0][j];
      candi[(size_t)row * cstride + coff + j] = li[0][j];
    }
  }
}

// ---------------- exact fp32 rescore of candidates -> top-3 ----------------
__global__ __launch_bounds__(64) void rescore_kernel(
    const float* __restrict__ q, const float* __restrict__ T,
    const float* __restrict__ candv, const int* __restrict__ candi, int candN,
    float* __restrict__ val, int* __restrict__ idx) {
  __shared__ int sel[8];
  __shared__ float sex[8];
  int row = blockIdx.x, tid = threadIdx.x;
  if (tid == 0) {
    float tv[8]; int ti[8];
#pragma unroll
    for (int j = 0; j < 8; ++j) { tv[j] = -__builtin_inff(); ti[j] = -1; }
    for (int c = 0; c < candN; ++c) {
      float d = candv[(size_t)row * candN + c];
      int di = candi[(size_t)row * candN + c];
      if (di >= 0 && d > tv[7]) {
        tv[7] = d; ti[7] = di;
#pragma unroll
        for (int j = 7; j > 0; --j) {
          if (tv[j] > tv[j - 1]) {
            float t = tv[j]; tv[j] = tv[j - 1]; tv[j - 1] = t;
            int t2 = ti[j]; ti[j] = ti[j - 1]; ti[j - 1] = t2;
          }
        }
      }
    }
#pragma unroll
    for (int j = 0; j < 8; ++j) sel[j] = ti[j];
  }
  __syncthreads();
  const float* qr = q + (size_t)row * CV;
  for (int c = 0; c < 8; ++c) {
    int n = sel[c];
    float part = 0.f;
    if (n >= 0) {
      const float* tr = T + (size_t)n * CV;
      int kb = tid * 12;
#pragma unroll
      for (int j3 = 0; j3 < 3; ++j3) {
        float4 a = *reinterpret_cast<const float4*>(tr + kb + j3 * 4);
        float4 b = *reinterpret_cast<const float4*>(qr + kb + j3 * 4);
        part += a.x * b.x + a.y * b.y + a.z * b.z + a.w * b.w;
      }
    }
#pragma unroll
    for (int off = 32; off >= 1; off >>= 1) part += __shfl_xor(part, off, 64);
    if (tid == 0) sex[c] = (n >= 0) ? part : -__builtin_inff();
  }
  __syncthreads();
  if (tid == 0) {
    for (int t = 0; t < 3; ++t) {
      float bv = -__builtin_inff(); int bi = 0x7fffffff, bc = -1;
      for (int c = 0; c < 8; ++c) {
        int di = sel[c];
        if (di < 0) continue;
        float v = sex[c];
        if (v > bv || (v == bv && di < bi)) { bv = v; bi = di; bc = c; }
      }
      val[row * 3 + t] = bv;
      idx[row * 3 + t] = bi;
      sel[bc] = -1;
    }
  }
}

// ---------------- combined (bf16, padded to KPAD1) ----------------
__global__ __launch_bounds__(256) void gather_concat_kernel(
    const float* __restrict__ v_seq, const float* __restrict__ nb,
    const float* __restrict__ val, const int* __restrict__ idx,
    u16* __restrict__ c16) {
  int row = blockIdx.x, tid = threadIdx.x;
  u16* c = c16 + (size_t)row * KPAD1;
  const float* vs = v_seq + (size_t)row * CV;
  if (tid < 192) {
    float4 v = *reinterpret_cast<const float4*>(vs + tid * 4);
    u16x4 o = {f2bf(v.x), f2bf(v.y), f2bf(v.z), f2bf(v.w)};
    *reinterpret_cast<u16x4*>(c + tid * 4) = o;
  }
  int i0 = idx[row * 3 + 0], i1 = idx[row * 3 + 1], i2 = idx[row * 3 + 2];
  if (tid < 75) {
    float4 v = *reinterpret_cast<const float4*>(nb + (size_t)i0 * DNB + tid * 4);
    u16x4 o = {f2bf(v.x), f2bf(v.y), f2bf(v.z), f2bf(v.w)};
    *reinterpret_cast<u16x4*>(c + CV + tid * 4) = o;
    v = *reinterpret_cast<const float4*>(nb + (size_t)i1 * DNB + tid * 4);
    o = {f2bf(v.x), f2bf(v.y), f2bf(v.z), f2bf(v.w)};
    *reinterpret_cast<u16x4*>(c + CV + DNB + tid * 4) = o;
    v = *reinterpret_cast<const float4*>(nb + (size_t)i2 * DNB + tid * 4);
    o = {f2bf(v.x), f2bf(v.y), f2bf(v.z), f2bf(v.w)};
    *reinterpret_cast<u16x4*>(c + CV + 2 * DNB + tid * 4) = o;
  }
  if (tid < 28) {  // val (3) + zero padding (25) at [1668, 1696)
    int o = CV + 3 * DNB + tid;
    c[o] = (tid < 3) ? f2bf(val[row * 3 + tid]) : (u16)0;
  }
}

// ---------------- in-place LayerNorm ----------------
__global__ __launch_bounds__(256) void layernorm_kernel(float* __restrict__ C) {
  __shared__ float ws[4];
  int row = blockIdx.x, tid = threadIdx.x;
  float* x = C + (size_t)row * CV;
  float x0 = x[tid], x1 = x[tid + 256], x2 = x[tid + 512];
  float mu = block_sum256(x0 + x1 + x2, ws) * (1.0f / 768.0f);
  float d0 = x0 - mu, d1 = x1 - mu, d2 = x2 - mu;
  float var = block_sum256(d0 * d0 + d1 * d1 + d2 * d2, ws) * (1.0f / 768.0f);
  float inv = 1.0f / sqrtf(var + 1e-5f);
  x[tid] = d0 * inv; x[tid + 256] = d1 * inv; x[tid + 512] = d2 * inv;
}

extern "C" void kernel_launch(void* const* d_in, const int* in_sizes, int n_in,
                              void* d_out, int out_size, void* d_ws, size_t ws_size,
                              hipStream_t stream) {
  const float* v_seq = (const float*)d_in[0];
  const float* T = (const float*)d_in[1];
  const float* nb = (const float*)d_in[2];
  const float* W1 = (const float*)d_in[3];
  const float* b1 = (const float*)d_in[4];
  const float* W2 = (const float*)d_in[5];
  const float* b2 = (const float*)d_in[6];
  float* out = (float*)d_out;

  char* base = (char*)d_ws;
  size_t off = 0;
  auto alloc = [&](size_t bytes) -> void* {
    void* p = base + off;
    off += (bytes + 255) & ~(size_t)255;
    return p;
  };
  float* q   = (float*)alloc((size_t)ROWS * CV * 4);
  u16* q16   = (u16*)alloc((size_t)ROWS * CV * 2);
  u16* T16   = (u16*)alloc((size_t)VOCAB * CV * 2);
  u16* c16   = (u16*)alloc((size_t)ROWS * KPAD1 * 2);
  u16* h16   = (u16*)alloc((size_t)ROWS * HD * 2);
  u16* W1T   = (u16*)alloc((size_t)HD * KPAD1 * 2);
  u16* W2T   = (u16*)alloc((size_t)HD * HD * 2);
  float* candv = (float*)alloc((size_t)ROWS * 256 * 4);
  int* candi   = (int*)alloc((size_t)ROWS * 256 * 4);
  float* val   = (float*)alloc((size_t)ROWS * 3 * 4);
  int* idxb    = (int*)alloc((size_t)ROWS * 3 * 4);
  float* Sc    = (float*)(base + off);

  // adaptive S-chunk width (multiple of 128) against remaining workspace
  size_t avail = (ws_size > off) ? (ws_size - off) : 0;
  long long wmax = (long long)(avail / ((size_t)ROWS * 4));
  wmax &= ~127LL;
  int W = (wmax > NPAD) ? NPAD : (int)wmax;
  if (W < 1664) W = 1664;                 // floor: 31 chunks max (248 candidates)
  int nch = (VOCAB + W - 1) / W;
  int candN = nch * 8;

  normalize_kernel<<<ROWS, 256, 0, stream>>>(v_seq, q, q16);
  cvt_bf16_kernel<<<2048, 256, 0, stream>>>(T, T16, VOCAB * CV / 4);
  transpose_cvt_kernel<<<dim3(KPAD1 / 32, HD / 32), 256, 0, stream>>>(W1, W1T, TOTAL_IN, KPAD1, HD);
  transpose_cvt_kernel<<<dim3(HD / 32, HD / 32), 256, 0, stream>>>(W2, W2T, HD, HD, HD);

  for (int c = 0; c < nch; ++c) {
    int nbase = c * W;
    int width = NPAD - nbase; if (width > W) width = W;
    int nv = VOCAB - nbase;   if (nv > width) nv = width;
    gemm_bt<0, 0><<<dim3(ROWS / 128, width / 128), 256, 0, stream>>>(
        q16, CV, T16, CV, VOCAB - 1, CV, nullptr, Sc, nullptr, width, nbase);
    topk8_chunk<<<ROWS, 256, 0, stream>>>(Sc, width, nv, nbase, candv, candi, candN, c * 8);
  }

  rescore_kernel<<<ROWS, 64, 0, stream>>>(q, T, candv, candi, candN, val, idxb);
  gather_concat_kernel<<<ROWS, 256, 0, stream>>>(v_seq, nb, val, idxb, c16);
  gemm_bt<1, 1><<<dim3(ROWS / 128, HD / 128), 256, 0, stream>>>(
      c16, KPAD1, W1T, KPAD1, HD - 1, KPAD1, b1, nullptr, h16, HD, 0);
  gemm_bt<0, 0><<<dim3(ROWS / 128, HD / 128), 256, 0, stream>>>(
      h16, HD, W2T, HD, HD - 1, HD, b2, out, nullptr, HD, 0);
  layernorm_kernel<<<ROWS, 256, 0, stream>>>(out);
}